// Round 1
// baseline (2402.700 us; speedup 1.0000x reference)
//
#include <hip/hip_runtime.h>

// EntailmentSelfAttention: N=16, L=256, S=2, H=16, D=64, E=1024
//
// Pipeline (all f32 this round; ws holds intermediates):
//   K1 k_proj    : vP/kP/qP[n][h][s][l][d] = row(values/keys/query) @ W^T
//   K2a k_energy : Et[nhs][l][q] = (kP[l]·qP[q])/32, masked by q -> -3.125e18
//   K2b k_softmax: row-softmax of Et over q (== reference softmax over axis 3)
//   K2c k_pv     : X[(n,q,s2)][e] = sum_l Et[l][q] * vP[l][d]  (interleaved e)
//   K3 k_wo      : out = X @ Wo^T + bo
//
// ws layout (f32 elements):
//   vP : 0            (8,388,608)
//   kP : 8,388,608    (8,388,608)   <- reused as X after k_energy consumes kP
//   qP : 16,777,216   (8,388,608)
//   Et : 25,165,824   (33,554,432)
// total 58,720,256 f32 = 224 MiB

#define NB 16
#define LL 256
#define SS 2
#define HH 16
#define DD 64
#define EE 1024

__global__ __launch_bounds__(256) void k_proj(
    const float* __restrict__ Av, const float* __restrict__ Ak,
    const float* __restrict__ Aq, const float* __restrict__ Wv,
    const float* __restrict__ Wk, const float* __restrict__ Wq,
    float* __restrict__ vP, float* __restrict__ kP, float* __restrict__ qP)
{
    __shared__ float As[3][64][36];
    __shared__ float Ws[3][64][36];
    const int b = blockIdx.x;
    const int h = b & 15, s = (b >> 4) & 1, lblk = (b >> 5) & 3, n = b >> 7;
    const int l0 = lblk * 64;
    const float* Asrc[3] = {Av, Ak, Aq};
    const float* Wsrc[3] = {Wv, Wk, Wq};
    float* Pdst[3] = {vP, kP, qP};
    const int tid = threadIdx.x;
    const int ty = tid >> 4, tx = tid & 15;

    float acc[3][4][4];
#pragma unroll
    for (int m = 0; m < 3; ++m)
#pragma unroll
        for (int i = 0; i < 4; ++i)
#pragma unroll
            for (int j = 0; j < 4; ++j) acc[m][i][j] = 0.f;

    const long baseA = (long)n * 524288 + (long)l0 * 2048 + s * 1024 + h * 64;

#pragma unroll
    for (int k0 = 0; k0 < 64; k0 += 32) {
        __syncthreads();
#pragma unroll
        for (int m = 0; m < 3; ++m) {
#pragma unroll
            for (int w = 0; w < 2; ++w) {
                int idx = w * 1024 + tid * 4;
                int r = idx >> 5, c = idx & 31;
                *(float4*)&As[m][r][c] =
                    *(const float4*)(Asrc[m] + baseA + (long)r * 2048 + k0 + c);
                *(float4*)&Ws[m][r][c] =
                    *(const float4*)(Wsrc[m] + r * 64 + k0 + c);
            }
        }
        __syncthreads();
#pragma unroll
        for (int kk = 0; kk < 32; kk += 4) {
            float4 a[3][4], wb[3][4];
#pragma unroll
            for (int m = 0; m < 3; ++m)
#pragma unroll
                for (int i = 0; i < 4; ++i)
                    a[m][i] = *(const float4*)&As[m][ty + 16 * i][kk];
#pragma unroll
            for (int m = 0; m < 3; ++m)
#pragma unroll
                for (int j = 0; j < 4; ++j)
                    wb[m][j] = *(const float4*)&Ws[m][tx + 16 * j][kk];
#pragma unroll
            for (int m = 0; m < 3; ++m)
#pragma unroll
                for (int i = 0; i < 4; ++i)
#pragma unroll
                    for (int j = 0; j < 4; ++j) {
                        acc[m][i][j] += a[m][i].x * wb[m][j].x;
                        acc[m][i][j] += a[m][i].y * wb[m][j].y;
                        acc[m][i][j] += a[m][i].z * wb[m][j].z;
                        acc[m][i][j] += a[m][i].w * wb[m][j].w;
                    }
        }
    }

    // vP/kP/qP layout: [n][h][s][l][d]  (slice of 256x64 contiguous per nhs)
    const long pbase = ((long)((n * 16 + h) * 2 + s)) * 16384 + (long)l0 * 64;
#pragma unroll
    for (int m = 0; m < 3; ++m)
#pragma unroll
        for (int i = 0; i < 4; ++i)
#pragma unroll
            for (int j = 0; j < 4; ++j)
                Pdst[m][pbase + (ty + 16 * i) * 64 + tx + 16 * j] = acc[m][i][j];
}

// 64x64 output tile per block, K=64 staged once. Low register pressure:
// acc[4][4] (16) + a[4]/bb[4] float4 (32) -> ~70 live VGPRs.
// Prev version (128x128 tile, acc[8][8] + a[8]/bb[8]) hit the 256-VGPR cap
// and spilled ~3 GB of scratch traffic to HBM (FETCH 1.89 GB / WRITE 1.64 GB
// vs 200 MB ideal) -> 1200 us. __launch_bounds__(256,4) pins VGPR <= 128.
// LDS 2*64*68*4 = 34.8 KB -> 4 blocks/CU.
__global__ __launch_bounds__(256, 4) void k_energy(
    const float* __restrict__ kP, const float* __restrict__ qP,
    const int* __restrict__ mask, float* __restrict__ Et)
{
    __shared__ float Ks[64][68];
    __shared__ float Qs[64][68];
    const int b = blockIdx.x;
    const int nhs = b >> 4, mblk = (b >> 2) & 3, nblk = b & 3;
    const int n = nhs >> 5, h = (nhs >> 1) & 15, s = nhs & 1;
    const int l0 = mblk * 64, q0 = nblk * 64;
    const long slice = (long)nhs * 16384;
    const int tid = threadIdx.x, ty = tid >> 4, tx = tid & 15;

    // stage whole K-tile (64x64) and Q-tile (64x64); one barrier total
#pragma unroll
    for (int w = 0; w < 4; ++w) {
        int idx = w * 1024 + tid * 4;
        int r = idx >> 6, c = idx & 63;
        *(float4*)&Ks[r][c] =
            *(const float4*)(kP + slice + (l0 + r) * 64 + c);
        *(float4*)&Qs[r][c] =
            *(const float4*)(qP + slice + (q0 + r) * 64 + c);
    }
    __syncthreads();

    float acc[4][4];
#pragma unroll
    for (int i = 0; i < 4; ++i)
#pragma unroll
        for (int j = 0; j < 4; ++j) acc[i][j] = 0.f;

#pragma unroll
    for (int kk = 0; kk < 64; kk += 4) {
        float4 a[4], bb[4];
#pragma unroll
        for (int i = 0; i < 4; ++i)
            a[i] = *(const float4*)&Ks[ty + 16 * i][kk];
#pragma unroll
        for (int j = 0; j < 4; ++j)
            bb[j] = *(const float4*)&Qs[tx + 16 * j][kk];
#pragma unroll
        for (int i = 0; i < 4; ++i)
#pragma unroll
            for (int j = 0; j < 4; ++j) {
                acc[i][j] += a[i].x * bb[j].x;
                acc[i][j] += a[i].y * bb[j].y;
                acc[i][j] += a[i].z * bb[j].z;
                acc[i][j] += a[i].w * bb[j].w;
            }
    }

    // mask depends only on q: mask[n, h>>3, 0, (h&7)*32 + s*16 + (q>>4)]
    const int mrow = n * 524288 + (h >> 3) * 262144 + (h & 7) * 32 + s * 16;
    float mbit[4];
#pragma unroll
    for (int j = 0; j < 4; ++j) {
        int q = q0 + tx + 16 * j;
        mbit[j] = (mask[mrow + (q >> 4)] != 0) ? 1.f : 0.f;
    }

    const long ebase = (long)nhs * 65536;
    const float scale = 0.03125f; // 1/sqrt(1024)
#pragma unroll
    for (int i = 0; i < 4; ++i)
#pragma unroll
        for (int j = 0; j < 4; ++j) {
            int l = l0 + ty + 16 * i, q = q0 + tx + 16 * j;
            float v = (mbit[j] != 0.f) ? acc[i][j] * scale : -3.125e18f;
            Et[ebase + l * 256 + q] = v;
        }
}

// row-softmax over q (reference softmax axis=3). One wave per row of 256.
__global__ __launch_bounds__(256) void k_softmax(float* __restrict__ Et)
{
    const int row = blockIdx.x * 4 + (threadIdx.x >> 6);
    const int lane = threadIdx.x & 63;
    float* p = Et + (long)row * 256 + lane * 4;
    float4 v = *(float4*)p;
    float m = fmaxf(fmaxf(v.x, v.y), fmaxf(v.z, v.w));
#pragma unroll
    for (int off = 1; off < 64; off <<= 1) m = fmaxf(m, __shfl_xor(m, off));
    float4 ex;
    ex.x = expf(v.x - m);
    ex.y = expf(v.y - m);
    ex.z = expf(v.z - m);
    ex.w = expf(v.w - m);
    float ssum = ex.x + ex.y + ex.z + ex.w;
#pragma unroll
    for (int off = 1; off < 64; off <<= 1) ssum += __shfl_xor(ssum, off);
    float inv = 1.0f / ssum;
    v.x = ex.x * inv; v.y = ex.y * inv; v.z = ex.z * inv; v.w = ex.w * inv;
    *(float4*)p = v;
}

// X[(n,q,s2)][e] = sum_l att[l][q] * vP[l][d], e = (h&7)*128 + 2d + s
__global__ __launch_bounds__(256) void k_pv(
    const float* __restrict__ Et, const float* __restrict__ vP,
    float* __restrict__ X)
{
    __shared__ float atts[32][260];
    __shared__ float vs[32][68];
    const int nhs = blockIdx.x;
    const int n = nhs >> 5, h = (nhs >> 1) & 15, s = nhs & 1;
    const long ebase = (long)nhs * 65536;
    const long vbase = (long)nhs * 16384;
    const int tid = threadIdx.x, ty = tid >> 3, tx = tid & 7;

    float acc[8][8];
#pragma unroll
    for (int i = 0; i < 8; ++i)
#pragma unroll
        for (int j = 0; j < 8; ++j) acc[i][j] = 0.f;

    for (int l0 = 0; l0 < 256; l0 += 32) {
        __syncthreads();
#pragma unroll
        for (int w = 0; w < 8; ++w) {
            int idx = w * 1024 + tid * 4;
            int lc = idx >> 8, qq = idx & 255;
            *(float4*)&atts[lc][qq] =
                *(const float4*)(Et + ebase + (l0 + lc) * 256 + qq);
        }
#pragma unroll
        for (int w = 0; w < 2; ++w) {
            int idx = w * 1024 + tid * 4;
            int lc = idx >> 6, dd = idx & 63;
            *(float4*)&vs[lc][dd] =
                *(const float4*)(vP + vbase + (l0 + lc) * 64 + dd);
        }
        __syncthreads();
#pragma unroll
        for (int lc = 0; lc < 32; ++lc) {
            float4 a0 = *(const float4*)&atts[lc][ty * 8];
            float4 a1 = *(const float4*)&atts[lc][ty * 8 + 4];
            float4 v0 = *(const float4*)&vs[lc][tx * 8];
            float4 v1 = *(const float4*)&vs[lc][tx * 8 + 4];
            float av[8] = {a0.x, a0.y, a0.z, a0.w, a1.x, a1.y, a1.z, a1.w};
            float vv[8] = {v0.x, v0.y, v0.z, v0.w, v1.x, v1.y, v1.z, v1.w};
#pragma unroll
            for (int i = 0; i < 8; ++i)
#pragma unroll
                for (int j = 0; j < 8; ++j) acc[i][j] += av[i] * vv[j];
        }
    }

    const int s2 = h >> 3, hr = h & 7;
#pragma unroll
    for (int i = 0; i < 8; ++i)
#pragma unroll
        for (int j = 0; j < 8; ++j) {
            int q = ty * 8 + i, d = tx * 8 + j;
            X[((long)((n * 256 + q) * 2 + s2)) * 1024 + hr * 128 + 2 * d + s] =
                acc[i][j];
        }
}

__global__ __launch_bounds__(256) void k_wo(
    const float* __restrict__ X, const float* __restrict__ Wo,
    const float* __restrict__ bo, float* __restrict__ out)
{
    __shared__ float Xs[128][36];
    __shared__ float Ws[128][36];
    const int b = blockIdx.x;
    const int by = b >> 3, bx = b & 7;
    const int r0 = by * 128, f0 = bx * 128;
    const int tid = threadIdx.x, ty = tid >> 4, tx = tid & 15;

    float acc[8][8];
#pragma unroll
    for (int i = 0; i < 8; ++i)
#pragma unroll
        for (int j = 0; j < 8; ++j) acc[i][j] = 0.f;

    for (int k0 = 0; k0 < 1024; k0 += 32) {
        __syncthreads();
#pragma unroll
        for (int w = 0; w < 4; ++w) {
            int idx = w * 1024 + tid * 4;
            int r = idx >> 5, c = idx & 31;
            *(float4*)&Xs[r][c] =
                *(const float4*)(X + (long)(r0 + r) * 1024 + k0 + c);
            *(float4*)&Ws[r][c] =
                *(const float4*)(Wo + (long)(f0 + r) * 1024 + k0 + c);
        }
        __syncthreads();
#pragma unroll
        for (int kk = 0; kk < 32; kk += 4) {
            float4 a[8], bb[8];
#pragma unroll
            for (int i = 0; i < 8; ++i)
                a[i] = *(const float4*)&Xs[ty + 16 * i][kk];
#pragma unroll
            for (int j = 0; j < 8; ++j)
                bb[j] = *(const float4*)&Ws[tx + 16 * j][kk];
#pragma unroll
            for (int i = 0; i < 8; ++i)
#pragma unroll
                for (int j = 0; j < 8; ++j) {
                    acc[i][j] += a[i].x * bb[j].x;
                    acc[i][j] += a[i].y * bb[j].y;
                    acc[i][j] += a[i].z * bb[j].z;
                    acc[i][j] += a[i].w * bb[j].w;
                }
        }
    }

#pragma unroll
    for (int i = 0; i < 8; ++i)
#pragma unroll
        for (int j = 0; j < 8; ++j) {
            int r = r0 + ty + 16 * i, f = f0 + tx + 16 * j;
            out[(long)r * 1024 + f] = acc[i][j] + bo[f];
        }
}

extern "C" void kernel_launch(void* const* d_in, const int* in_sizes, int n_in,
                              void* d_out, int out_size, void* d_ws,
                              size_t ws_size, hipStream_t stream)
{
    const float* vals = (const float*)d_in[0];
    const float* keys = (const float*)d_in[1];
    const float* qrys = (const float*)d_in[2];
    const int*   mask = (const int*)d_in[3];
    const float* Wv   = (const float*)d_in[4];
    const float* Wk   = (const float*)d_in[5];
    const float* Wq   = (const float*)d_in[6];
    const float* Wo   = (const float*)d_in[7];
    const float* bo   = (const float*)d_in[8];
    float* ws  = (float*)d_ws;
    float* vP  = ws;
    float* kP  = ws + 8388608;
    float* qP  = ws + 16777216;
    float* Et  = ws + 25165824;
    float* X   = ws + 8388608;   // aliases kP (dead after k_energy)
    float* out = (float*)d_out;

    k_proj<<<2048, 256, 0, stream>>>(vals, keys, qrys, Wv, Wk, Wq, vP, kP, qP);
    k_energy<<<8192, 256, 0, stream>>>(kP, qP, mask, Et);
    k_softmax<<<32768, 256, 0, stream>>>(Et);
    k_pv<<<512, 256, 0, stream>>>(Et, vP, X);
    k_wo<<<512, 256, 0, stream>>>(X, Wo, bo, out);
}

// Round 2
// 1725.288 us; speedup vs baseline: 1.3926x; 1.3926x over previous
//
#include <hip/hip_runtime.h>

// EntailmentSelfAttention: N=16, L=256, S=2, H=16, D=64, E=1024
//
// Pipeline:
//   K1 k_proj : vP/kP/qP[n][h][s][l][d] = row(values/keys/query) @ W^T
//   K2 k_attn : FUSED energy+softmax+PV per (n,h,s) slice.
//               Softmax axis is q (per-l normalization); PV sums over l,
//               so each 32-row l-chunk is independent: compute S-chunk in
//               LDS, row-softmax it, accumulate X += att^T * V. Et never
//               touches global memory (rounds 0/1: Et materialization drove
//               3.6-6.7 GB of unexplainable traffic and 1200-1880 us).
//   K3 k_wo   : out = X @ Wo^T + bo
//
// ws layout (f32 elements):
//   vP : 0            (8,388,608)
//   kP : 8,388,608    (8,388,608)
//   qP : 16,777,216   (8,388,608)
//   X  : 25,165,824   (8,388,608)   (was Et's slot; no aliasing with v/k/qP)
// total 33,554,432 f32 = 128 MiB

__global__ __launch_bounds__(256) void k_proj(
    const float* __restrict__ Av, const float* __restrict__ Ak,
    const float* __restrict__ Aq, const float* __restrict__ Wv,
    const float* __restrict__ Wk, const float* __restrict__ Wq,
    float* __restrict__ vP, float* __restrict__ kP, float* __restrict__ qP)
{
    __shared__ float As[3][64][36];
    __shared__ float Ws[3][64][36];
    const int b = blockIdx.x;
    const int h = b & 15, s = (b >> 4) & 1, lblk = (b >> 5) & 3, n = b >> 7;
    const int l0 = lblk * 64;
    const float* Asrc[3] = {Av, Ak, Aq};
    const float* Wsrc[3] = {Wv, Wk, Wq};
    float* Pdst[3] = {vP, kP, qP};
    const int tid = threadIdx.x;
    const int ty = tid >> 4, tx = tid & 15;

    float acc[3][4][4];
#pragma unroll
    for (int m = 0; m < 3; ++m)
#pragma unroll
        for (int i = 0; i < 4; ++i)
#pragma unroll
            for (int j = 0; j < 4; ++j) acc[m][i][j] = 0.f;

    const long baseA = (long)n * 524288 + (long)l0 * 2048 + s * 1024 + h * 64;

#pragma unroll
    for (int k0 = 0; k0 < 64; k0 += 32) {
        __syncthreads();
#pragma unroll
        for (int m = 0; m < 3; ++m) {
#pragma unroll
            for (int w = 0; w < 2; ++w) {
                int idx = w * 1024 + tid * 4;
                int r = idx >> 5, c = idx & 31;
                *(float4*)&As[m][r][c] =
                    *(const float4*)(Asrc[m] + baseA + (long)r * 2048 + k0 + c);
                *(float4*)&Ws[m][r][c] =
                    *(const float4*)(Wsrc[m] + r * 64 + k0 + c);
            }
        }
        __syncthreads();
#pragma unroll
        for (int kk = 0; kk < 32; kk += 4) {
            float4 a[3][4], wb[3][4];
#pragma unroll
            for (int m = 0; m < 3; ++m)
#pragma unroll
                for (int i = 0; i < 4; ++i)
                    a[m][i] = *(const float4*)&As[m][ty + 16 * i][kk];
#pragma unroll
            for (int m = 0; m < 3; ++m)
#pragma unroll
                for (int j = 0; j < 4; ++j)
                    wb[m][j] = *(const float4*)&Ws[m][tx + 16 * j][kk];
#pragma unroll
            for (int m = 0; m < 3; ++m)
#pragma unroll
                for (int i = 0; i < 4; ++i)
#pragma unroll
                    for (int j = 0; j < 4; ++j) {
                        acc[m][i][j] += a[m][i].x * wb[m][j].x;
                        acc[m][i][j] += a[m][i].y * wb[m][j].y;
                        acc[m][i][j] += a[m][i].z * wb[m][j].z;
                        acc[m][i][j] += a[m][i].w * wb[m][j].w;
                    }
        }
    }

    // vP/kP/qP layout: [n][h][s][l][d]  (slice of 256x64 contiguous per nhs)
    const long pbase = ((long)((n * 16 + h) * 2 + s)) * 16384 + (long)l0 * 64;
#pragma unroll
    for (int m = 0; m < 3; ++m)
#pragma unroll
        for (int i = 0; i < 4; ++i)
#pragma unroll
            for (int j = 0; j < 4; ++j)
                Pdst[m][pbase + (ty + 16 * i) * 64 + tx + 16 * j] = acc[m][i][j];
}

// Fused attention per nhs slice. 512 threads (8 waves), ~118 KB LDS,
// 1 block/CU (LDS-limited). Per 32-row l-chunk:
//   sync; stage K/V chunk; sync; S = K_chunk*Q^T (raw, masked) -> atts;
//   sync; per-row max/sum + atts = exp(s-m)/Z (wave-per-4-rows);
//   sync; acc[q][d] += atts^T * V_chunk.
// Global traffic per block: Q 64K + K 64K + V 64K read, X 64K write.
__global__ __launch_bounds__(512) void k_attn(
    const float* __restrict__ kP, const float* __restrict__ qP,
    const float* __restrict__ vP, const int* __restrict__ mask,
    float* __restrict__ X)
{
    __shared__ float Qs[256][68];    // 69,632 B
    __shared__ float Ks[32][68];     //  8,704 B
    __shared__ float vs[32][68];     //  8,704 B
    __shared__ float atts[32][260];  // 33,280 B

    const int nhs = blockIdx.x;
    const int n = nhs >> 5, h = (nhs >> 1) & 15, s = nhs & 1;
    const long slice = (long)nhs * 16384;
    const int tid = threadIdx.x;

    // ---- stage Q (256x64) once; covered by the first in-loop barrier
#pragma unroll
    for (int w = 0; w < 8; ++w) {
        int idx = w * 2048 + tid * 4;
        int r = idx >> 6, c = idx & 63;
        *(float4*)&Qs[r][c] = *(const float4*)(qP + slice + r * 64 + c);
    }

    // GEMM thread map: l = gty + 8*i (i<4), q = gtx + 64*j (j<4)
    const int gty = tid >> 6;   // == wave id, 0..7 -> Ks reads broadcast
    const int gtx = tid & 63;
    // mask depends only on q: mask[n, h>>3, 0, (h&7)*32 + s*16 + (q>>4)]
    const int mrow = n * 524288 + (h >> 3) * 262144 + (h & 7) * 32 + s * 16;
    float mbit[4];
#pragma unroll
    for (int j = 0; j < 4; ++j) {
        int q = gtx + 64 * j;
        mbit[j] = (mask[mrow + (q >> 4)] != 0) ? 1.f : 0.f;
    }

    // PV thread map: q = pty*4 + i (i<4), d = ptx*8 + j (j<8)
    const int pty = tid >> 3, ptx = tid & 7;
    float acc[4][8];
#pragma unroll
    for (int i = 0; i < 4; ++i)
#pragma unroll
        for (int j = 0; j < 8; ++j) acc[i][j] = 0.f;

    // staging map for K/V chunk: one float4/thread
    const int sr = tid >> 4, sc = (tid & 15) * 4;
    // stats map: wave w handles rows 4w..4w+3
    const int lane = tid & 63;

    const float scale = 0.03125f; // 1/sqrt(1024)

    for (int lc0 = 0; lc0 < 256; lc0 += 32) {
        __syncthreads();  // prev PV done reading Ks/vs/atts; Qs ready (iter 0)
        *(float4*)&Ks[sr][sc] =
            *(const float4*)(kP + slice + (lc0 + sr) * 64 + sc);
        *(float4*)&vs[sr][sc] =
            *(const float4*)(vP + slice + (lc0 + sr) * 64 + sc);
        __syncthreads();

        // ---- S-chunk GEMM (32 x 256 x 64)
        float sacc[4][4];
#pragma unroll
        for (int i = 0; i < 4; ++i)
#pragma unroll
            for (int j = 0; j < 4; ++j) sacc[i][j] = 0.f;
#pragma unroll
        for (int kk = 0; kk < 64; kk += 4) {
            float4 a[4], bb[4];
#pragma unroll
            for (int i = 0; i < 4; ++i)
                a[i] = *(const float4*)&Ks[gty + 8 * i][kk];
#pragma unroll
            for (int j = 0; j < 4; ++j)
                bb[j] = *(const float4*)&Qs[gtx + 64 * j][kk];
#pragma unroll
            for (int i = 0; i < 4; ++i)
#pragma unroll
                for (int j = 0; j < 4; ++j) {
                    sacc[i][j] += a[i].x * bb[j].x;
                    sacc[i][j] += a[i].y * bb[j].y;
                    sacc[i][j] += a[i].z * bb[j].z;
                    sacc[i][j] += a[i].w * bb[j].w;
                }
        }
        // masked scale, raw scores into LDS
#pragma unroll
        for (int i = 0; i < 4; ++i)
#pragma unroll
            for (int j = 0; j < 4; ++j)
                atts[gty + 8 * i][gtx + 64 * j] =
                    (mbit[j] != 0.f) ? sacc[i][j] * scale : -3.125e18f;
        __syncthreads();

        // ---- row softmax over q (axis 3 of reference): wave per 4 rows
#pragma unroll
        for (int rr = 0; rr < 4; ++rr) {
            const int r = gty * 4 + rr;
            float4 v = *(const float4*)&atts[r][lane * 4];
            float m = fmaxf(fmaxf(v.x, v.y), fmaxf(v.z, v.w));
#pragma unroll
            for (int off = 1; off < 64; off <<= 1)
                m = fmaxf(m, __shfl_xor(m, off));
            float4 e;
            e.x = expf(v.x - m);
            e.y = expf(v.y - m);
            e.z = expf(v.z - m);
            e.w = expf(v.w - m);
            float zs = e.x + e.y + e.z + e.w;
#pragma unroll
            for (int off = 1; off < 64; off <<= 1) zs += __shfl_xor(zs, off);
            const float iz = 1.0f / zs;
            e.x *= iz; e.y *= iz; e.z *= iz; e.w *= iz;
            *(float4*)&atts[r][lane * 4] = e;
        }
        __syncthreads();

        // ---- PV accumulate: acc[q][d] += atts[lc][q] * vs[lc][d]
#pragma unroll
        for (int lc = 0; lc < 32; ++lc) {
            float4 a0 = *(const float4*)&atts[lc][pty * 4];
            float4 v0 = *(const float4*)&vs[lc][ptx * 8];
            float4 v1 = *(const float4*)&vs[lc][ptx * 8 + 4];
            float av[4] = {a0.x, a0.y, a0.z, a0.w};
            float vv[8] = {v0.x, v0.y, v0.z, v0.w, v1.x, v1.y, v1.z, v1.w};
#pragma unroll
            for (int i = 0; i < 4; ++i)
#pragma unroll
                for (int j = 0; j < 8; ++j) acc[i][j] += av[i] * vv[j];
        }
    }

    // ---- write X[(n,q,s2)][e], e = hr*128 + 2d + s
    const int s2 = h >> 3, hr = h & 7;
#pragma unroll
    for (int i = 0; i < 4; ++i)
#pragma unroll
        for (int j = 0; j < 8; ++j) {
            int q = pty * 4 + i, d = ptx * 8 + j;
            X[((long)((n * 256 + q) * 2 + s2)) * 1024 + hr * 128 + 2 * d + s] =
                acc[i][j];
        }
}

__global__ __launch_bounds__(256) void k_wo(
    const float* __restrict__ X, const float* __restrict__ Wo,
    const float* __restrict__ bo, float* __restrict__ out)
{
    __shared__ float Xs[128][36];
    __shared__ float Ws[128][36];
    const int b = blockIdx.x;
    const int by = b >> 3, bx = b & 7;
    const int r0 = by * 128, f0 = bx * 128;
    const int tid = threadIdx.x, ty = tid >> 4, tx = tid & 15;

    float acc[8][8];
#pragma unroll
    for (int i = 0; i < 8; ++i)
#pragma unroll
        for (int j = 0; j < 8; ++j) acc[i][j] = 0.f;

    for (int k0 = 0; k0 < 1024; k0 += 32) {
        __syncthreads();
#pragma unroll
        for (int w = 0; w < 4; ++w) {
            int idx = w * 1024 + tid * 4;
            int r = idx >> 5, c = idx & 31;
            *(float4*)&Xs[r][c] =
                *(const float4*)(X + (long)(r0 + r) * 1024 + k0 + c);
            *(float4*)&Ws[r][c] =
                *(const float4*)(Wo + (long)(f0 + r) * 1024 + k0 + c);
        }
        __syncthreads();
#pragma unroll
        for (int kk = 0; kk < 32; kk += 4) {
            float4 a[8], bb[8];
#pragma unroll
            for (int i = 0; i < 8; ++i)
                a[i] = *(const float4*)&Xs[ty + 16 * i][kk];
#pragma unroll
            for (int j = 0; j < 8; ++j)
                bb[j] = *(const float4*)&Ws[tx + 16 * j][kk];
#pragma unroll
            for (int i = 0; i < 8; ++i)
#pragma unroll
                for (int j = 0; j < 8; ++j) {
                    acc[i][j] += a[i].x * bb[j].x;
                    acc[i][j] += a[i].y * bb[j].y;
                    acc[i][j] += a[i].z * bb[j].z;
                    acc[i][j] += a[i].w * bb[j].w;
                }
        }
    }

#pragma unroll
    for (int i = 0; i < 8; ++i)
#pragma unroll
        for (int j = 0; j < 8; ++j) {
            int r = r0 + ty + 16 * i, f = f0 + tx + 16 * j;
            out[(long)r * 1024 + f] = acc[i][j] + bo[f];
        }
}

extern "C" void kernel_launch(void* const* d_in, const int* in_sizes, int n_in,
                              void* d_out, int out_size, void* d_ws,
                              size_t ws_size, hipStream_t stream)
{
    const float* vals = (const float*)d_in[0];
    const float* keys = (const float*)d_in[1];
    const float* qrys = (const float*)d_in[2];
    const int*   mask = (const int*)d_in[3];
    const float* Wv   = (const float*)d_in[4];
    const float* Wk   = (const float*)d_in[5];
    const float* Wq   = (const float*)d_in[6];
    const float* Wo   = (const float*)d_in[7];
    const float* bo   = (const float*)d_in[8];
    float* ws  = (float*)d_ws;
    float* vP  = ws;
    float* kP  = ws + 8388608;
    float* qP  = ws + 16777216;
    float* X   = ws + 25165824;   // own region; no aliasing with vP/kP/qP
    float* out = (float*)d_out;

    k_proj<<<2048, 256, 0, stream>>>(vals, keys, qrys, Wv, Wk, Wq, vP, kP, qP);
    k_attn<<<512, 512, 0, stream>>>(kP, qP, vP, mask, X);
    k_wo<<<512, 256, 0, stream>>>(X, Wo, bo, out);
}